// Round 21
// baseline (833.509 us; speedup 1.0000x reference)
//
#include <hip/hip_runtime.h>
#include <hip/hip_bf16.h>
#include <hip/hip_cooperative_groups.h>

namespace cg = cooperative_groups;

#define H 128
#define D_IN 256
#define NGRAPH 8

typedef __attribute__((ext_vector_type(8))) short bf16x8;
typedef __attribute__((ext_vector_type(4))) float f32x4;
typedef __attribute__((ext_vector_type(4))) int i32x4;

__device__ __forceinline__ unsigned fenc(float f) {
  unsigned u = __float_as_uint(f);
  return (u & 0x80000000u) ? ~u : (u | 0x80000000u);
}
__device__ __forceinline__ float fdec(unsigned e) {
  unsigned v = (e & 0x80000000u) ? (e & 0x7FFFFFFFu) : ~e;
  return __uint_as_float(v);
}
__device__ __forceinline__ unsigned short f2bf(float f) {  // RNE f32->bf16
  unsigned u = __float_as_uint(f);
  unsigned r = u + 0x7FFFu + ((u >> 16) & 1u);
  return (unsigned short)(r >> 16);
}
__device__ __forceinline__ void gload16(const void* gsrc, void* ldst) {
  __builtin_amdgcn_global_load_lds(
      (const __attribute__((address_space(1))) unsigned int*)gsrc,
      (__attribute__((address_space(3))) unsigned int*)ldst, 16, 0, 0);
}

// ---------- shared device bodies (used by BOTH mega and fallback paths) ----

template <int K, bool AF32, bool FIRST>
__device__ void gemm_tile(int tile, const void* Ain, const unsigned short* Bpack,
                          const float* bias, const float* bn, const float* wlin,
                          float blinv, const int* batch, unsigned short* hout,
                          float* node_pred, unsigned* wsiL, int N,
                          char* s_a, float (*s_head)[2], unsigned* s_wsi) {
  constexpr int RB = 256;
  constexpr int ROWBYTES = AF32 ? K * 4 : K * 2;
  constexpr int NCHUNK = ROWBYTES / RB;
  constexpr int SPC = AF32 ? 2 : 4;
  const int tid = threadIdx.x;
  const int wid = tid >> 6, lane = tid & 63;
  const int wr = wid >> 1, wc = wid & 1;
  const int g = lane >> 4, l15 = lane & 15;
  const int row0blk = tile * 64;

  __syncthreads();                 // LDS safe to reuse from previous tile/phase
  if (tid < NGRAPH) s_wsi[tid] = 0u;

  f32x4 acc[2][4] = {};
  const int lrow0 = wr * 32;
  const char* Ab = (const char*)Ain;

  for (int ch = 0; ch < NCHUNK; ++ch) {
#pragma unroll
    for (int it = 0; it < 4; ++it) {
      int unit = it * 256 + tid;
      int lr = unit >> 4;
      int cb = (unit & 15) * 16;
      int grow = row0blk + lr;
      grow = (grow < N) ? grow : (N - 1);
      int gcol = cb ^ ((lr & 7) << 4);
      gload16(Ab + (size_t)grow * ROWBYTES + ch * RB + gcol,
              s_a + (it * 256 + wid * 64) * 16);
    }
    __syncthreads();

#pragma unroll
    for (int s = 0; s < SPC; ++s) {
      int sg = ch * SPC + s;
      bf16x8 bfr[4];
#pragma unroll
      for (int n = 0; n < 4; ++n) {
        int c = wc * 64 + n * 16 + l15;
        bfr[n] = *(const bf16x8*)(Bpack + sg * 4096 + c * 32 + g * 8);
      }
      bf16x8 af[2];
#pragma unroll
      for (int m = 0; m < 2; ++m) {
        int lr = lrow0 + m * 16 + l15;
        int sw = (lr & 7) << 4;
        if (AF32) {
          int c0 = s * 128 + g * 32;
          f32x4 u0 = *(const f32x4*)(s_a + lr * RB + (c0 ^ sw));
          f32x4 u1 = *(const f32x4*)(s_a + lr * RB + ((c0 + 16) ^ sw));
          union { unsigned short hh[8]; bf16x8 v; } pk;
          pk.hh[0] = f2bf(u0[0]); pk.hh[1] = f2bf(u0[1]);
          pk.hh[2] = f2bf(u0[2]); pk.hh[3] = f2bf(u0[3]);
          pk.hh[4] = f2bf(u1[0]); pk.hh[5] = f2bf(u1[1]);
          pk.hh[6] = f2bf(u1[2]); pk.hh[7] = f2bf(u1[3]);
          af[m] = pk.v;
        } else {
          int c0 = s * 64 + g * 16;
          af[m] = *(const bf16x8*)(s_a + lr * RB + (c0 ^ sw));
        }
      }
#pragma unroll
      for (int m = 0; m < 2; ++m)
#pragma unroll
        for (int n = 0; n < 4; ++n)
          acc[m][n] = __builtin_amdgcn_mfma_f32_16x16x32_bf16(af[m], bfr[n], acc[m][n], 0, 0, 0);
    }
    __syncthreads();
  }

  float sc[4], sh[4], wl[4];
#pragma unroll
  for (int n = 0; n < 4; ++n) {
    int c = wc * 64 + n * 16 + l15;
    float gam = bn[c], bet = bn[H + c], mu = bn[2 * H + c], va = bn[3 * H + c];
    float rs = rsqrtf(va + 1e-5f);
    sc[n] = gam * rs;
    sh[n] = (bias[c] - mu) * gam * rs + bet;
    wl[n] = wlin[c];
  }

  char* aw = s_a + wid * 2048;
#pragma unroll
  for (int m = 0; m < 2; ++m) {
    float pj[4] = {0.f, 0.f, 0.f, 0.f};
#pragma unroll
    for (int n = 0; n < 4; ++n)
#pragma unroll
      for (int j = 0; j < 4; ++j) {
        float hv = fmaxf(acc[m][n][j] * sc[n] + sh[n], 0.f);
        pj[j] += hv * wl[n];
        *(unsigned short*)(aw + (g * 4 + j) * 128 + (n * 16 + l15) * 2) = f2bf(hv);
      }
#pragma unroll
    for (int j = 0; j < 4; ++j) {
      pj[j] += __shfl_xor(pj[j], 1);
      pj[j] += __shfl_xor(pj[j], 2);
      pj[j] += __shfl_xor(pj[j], 4);
      pj[j] += __shfl_xor(pj[j], 8);
    }
    if (l15 == 0) {
#pragma unroll
      for (int j = 0; j < 4; ++j)
        s_head[wr * 32 + m * 16 + g * 4 + j][wc] = pj[j];
    }
    int grb = row0blk + wr * 32 + m * 16;
#pragma unroll
    for (int it = 0; it < 2; ++it) {
      int bo = lane * 16 + it * 1024;
      int r16 = bo >> 7, inrow = bo & 127;
      if (grb + r16 < N)
        *(i32x4*)((char*)hout + (size_t)(grb + r16) * 256 + wc * 128 + inrow) =
            *(i32x4*)(aw + bo);
    }
  }
  __syncthreads();
  if (tid < 64) {
    int grh = row0blk + tid;
    if (grh < N) {
      float np = s_head[tid][0] + s_head[tid][1] + blinv;
      if (FIRST) node_pred[grh] = np; else node_pred[grh] += np;
      atomicMax(&s_wsi[batch[grh]], fenc(np));
    }
  }
  __syncthreads();
  if (tid < NGRAPH && s_wsi[tid] != 0u) atomicMax(&wsiL[tid], s_wsi[tid]);
}

__device__ void agg_body(const unsigned short* h, const int* offsets, const int* esrc,
                         unsigned short* tmp, int N) {
  const int tid = threadIdx.x;
  const int wid = tid >> 6, lane = tid & 63;
  const int stride = gridDim.x * 4;
  const unsigned* hw = (const unsigned*)h;
  for (int node = blockIdx.x * 4 + wid; node < N; node += stride) {
    size_t base = (size_t)node * 64 + lane;
    unsigned u = hw[base];
    float a0 = __uint_as_float((u & 0xFFFFu) << 16);
    float a1 = __uint_as_float(u & 0xFFFF0000u);
    int s = offsets[node], e = offsets[node + 1];
    int j = s;
    for (; j + 4 <= e; j += 4) {
      int i0 = esrc[j], i1 = esrc[j + 1], i2 = esrc[j + 2], i3 = esrc[j + 3];
      unsigned v0 = hw[(size_t)i0 * 64 + lane];
      unsigned v1 = hw[(size_t)i1 * 64 + lane];
      unsigned v2 = hw[(size_t)i2 * 64 + lane];
      unsigned v3 = hw[(size_t)i3 * 64 + lane];
      a0 += __uint_as_float((v0 & 0xFFFFu) << 16) + __uint_as_float((v1 & 0xFFFFu) << 16) +
            __uint_as_float((v2 & 0xFFFFu) << 16) + __uint_as_float((v3 & 0xFFFFu) << 16);
      a1 += __uint_as_float(v0 & 0xFFFF0000u) + __uint_as_float(v1 & 0xFFFF0000u) +
            __uint_as_float(v2 & 0xFFFF0000u) + __uint_as_float(v3 & 0xFFFF0000u);
    }
    for (; j < e; ++j) {
      unsigned v = hw[(size_t)esrc[j] * 64 + lane];
      a0 += __uint_as_float((v & 0xFFFFu) << 16);
      a1 += __uint_as_float(v & 0xFFFF0000u);
    }
    ((unsigned*)tmp)[base] = ((unsigned)f2bf(a1) << 16) | (unsigned)f2bf(a0);
  }
}

__device__ void pack_weights_body(int i, const float* wf, const float* wcv,
                                  unsigned short* Bf, unsigned short* Bc) {
  if (i < 32768) {
    int s = i >> 12, r = i & 4095;
    int c = r >> 5, r2 = r & 31;
    int g = r2 >> 3, j = r2 & 7;
    int k = s * 32 + g * 8 + j;
    Bf[i] = f2bf(wf[k * H + c]);
  } else if (i < 65536) {
    int i2 = i - 32768;
    int l = i2 >> 14, r = i2 & 16383;
    int s = r >> 12, rr = r & 4095;
    int c = rr >> 5, r2 = rr & 31;
    int g = r2 >> 3, j = r2 & 7;
    int k = s * 32 + g * 8 + j;
    Bc[i2] = f2bf(wcv[l * H * H + k * H + c]);
  }
}

// ---------------------------- mega (cooperative) ---------------------------

struct KArgs {
  const float* x;
  const int* src;
  const int* dst;
  const int* batch;
  const float* w_first;
  const float* b_first;
  const float* bn_first;
  const float* w_conv;
  const float* b_conv;
  const float* bn_conv;
  const float* w_lin;
  const float* b_lin;
  float* out;
  unsigned short* h;
  unsigned short* tmp;
  unsigned short* wTf;
  unsigned short* wTc;
  int* offsets;
  int* cursor;
  int* esrc;
  int* csum;
  unsigned* wsi;   // [3][8]
  int N, E, ntiles, nchunks;
};

__global__ void __launch_bounds__(256)
mega_kernel(KArgs a) {
  cg::grid_group grid = cg::this_grid();
  __shared__ char s_a[16384];
  __shared__ float s_head[64][2];
  __shared__ unsigned s_wsi[NGRAPH];
  int* s_scan = (int*)s_a;              // phase-2 scratch (aliases s_a)
  int* s_c2 = (int*)(s_a + 1024);       // phase-3 scratch (512 ints)

  const int tid = threadIdx.x;
  const int bid = blockIdx.x;
  const int gtid = bid * 256 + tid;
  const int gstride = gridDim.x * 256;
  const int n1 = a.N + 1;

  // Phase 0: init offsets + wsi, pack weights
  for (int i = gtid; i < n1; i += gstride) a.offsets[i] = 0;
  if (gtid < 3 * NGRAPH) a.wsi[gtid] = 0u;
  for (int i = gtid; i < 65536; i += gstride)
    pack_weights_body(i, a.w_first, a.w_conv, a.wTf, a.wTc);
  grid.sync();

  // Phase 1: count in-degrees
  for (int e = gtid; e < a.E; e += gstride) atomicAdd(&a.offsets[a.dst[e]], 1);
  grid.sync();

  // Phase 2: per-256-chunk exclusive scan; chunk totals -> csum
  for (int ch = bid; ch < a.nchunks; ch += gridDim.x) {
    int i = ch * 256 + tid;
    int v = (i < n1) ? a.offsets[i] : 0;
    s_scan[tid] = v;
    __syncthreads();
    for (int off = 1; off < 256; off <<= 1) {
      int t = (tid >= off) ? s_scan[tid - off] : 0;
      __syncthreads();
      s_scan[tid] += t;
      __syncthreads();
    }
    if (i < n1) a.offsets[i] = s_scan[tid] - v;
    if (tid == 255) a.csum[ch] = s_scan[255];
    __syncthreads();
  }
  grid.sync();

  // Phase 3: block 0 exclusive-scans chunk totals (<=512)
  if (bid == 0) {
    for (int k = tid; k < 512; k += 256) s_c2[k] = (k < a.nchunks) ? a.csum[k] : 0;
    __syncthreads();
    for (int off = 1; off < 512; off <<= 1) {
      int t0 = (tid >= off) ? s_c2[tid - off] : 0;
      int t1 = ((tid + 256) >= off) ? s_c2[tid + 256 - off] : 0;
      __syncthreads();
      s_c2[tid] += t0;
      s_c2[tid + 256] += t1;
      __syncthreads();
    }
    for (int k = tid; k < a.nchunks; k += 256) a.csum[k] = (k == 0) ? 0 : s_c2[k - 1];
  }
  grid.sync();

  // Phase 4: add chunk bases; copy to cursor
  for (int i = gtid; i < n1; i += gstride) {
    int v = a.offsets[i] + a.csum[i >> 8];
    a.offsets[i] = v;
    if (i < a.N) a.cursor[i] = v;
  }
  grid.sync();

  // Phase 5: fill CSR
  for (int e = gtid; e < a.E; e += gstride) {
    int d = a.dst[e];
    int p = atomicAdd(&a.cursor[d], 1);
    a.esrc[p] = a.src[e];
  }
  grid.sync();

  float* node_pred = a.out + NGRAPH;

  // Phase 6: first-layer GEMM (x f32 -> h)
  for (int t = bid; t < a.ntiles; t += gridDim.x)
    gemm_tile<D_IN, true, true>(t, a.x, a.wTf, a.b_first, a.bn_first, a.w_lin,
                                a.b_lin[0], a.batch, a.h, node_pred, a.wsi, a.N,
                                s_a, s_head, s_wsi);
  grid.sync();

  // Phase 7: agg (h -> tmp)
  agg_body(a.h, a.offsets, a.esrc, a.tmp, a.N);
  grid.sync();

  // Phase 8: conv1 (tmp -> h)
  for (int t = bid; t < a.ntiles; t += gridDim.x)
    gemm_tile<H, false, false>(t, a.tmp, a.wTc, a.b_conv, a.bn_conv, a.w_lin + H,
                               a.b_lin[1], a.batch, a.h, node_pred, a.wsi + NGRAPH, a.N,
                               s_a, s_head, s_wsi);
  grid.sync();

  // Phase 9: agg (h -> tmp)
  agg_body(a.h, a.offsets, a.esrc, a.tmp, a.N);
  grid.sync();

  // Phase 10: conv2 (tmp -> h)
  for (int t = bid; t < a.ntiles; t += gridDim.x)
    gemm_tile<H, false, false>(t, a.tmp, a.wTc + 16384, a.b_conv + H, a.bn_conv + 4 * H,
                               a.w_lin + 2 * H, a.b_lin[2], a.batch, a.h, node_pred,
                               a.wsi + 2 * NGRAPH, a.N, s_a, s_head, s_wsi);
  grid.sync();

  // Phase 11: finalize
  if (bid == 0 && tid < NGRAPH)
    a.out[tid] = fdec(a.wsi[tid]) + fdec(a.wsi[NGRAPH + tid]) + fdec(a.wsi[2 * NGRAPH + tid]);
}

// ---------------------------- fallback kernels -----------------------------

__global__ void init_prep_kernel(int* __restrict__ offsets, int n1, unsigned* __restrict__ wsi,
                                 const float* __restrict__ wf, const float* __restrict__ wcv,
                                 unsigned short* __restrict__ Bf, unsigned short* __restrict__ Bc) {
  int i = blockIdx.x * 256 + threadIdx.x;
  if (i < n1) offsets[i] = 0;
  if (i < 3 * NGRAPH) wsi[i] = 0u;
  pack_weights_body(i, wf, wcv, Bf, Bc);
}

__global__ void count_kernel(const int* __restrict__ dst, int* __restrict__ offsets, int E) {
  int i = blockIdx.x * blockDim.x + threadIdx.x;
  int stride = gridDim.x * blockDim.x;
  for (int e = i; e < E; e += stride) atomicAdd(&offsets[dst[e]], 1);
}

__global__ void __launch_bounds__(1024)
scan_local(int* __restrict__ data, int* __restrict__ bsum, int n) {
  __shared__ int s[1024];
  int tid = threadIdx.x;
  int i = blockIdx.x * 1024 + tid;
  int v = (i < n) ? data[i] : 0;
  s[tid] = v;
  __syncthreads();
  for (int off = 1; off < 1024; off <<= 1) {
    int t = (tid >= off) ? s[tid - off] : 0;
    __syncthreads();
    s[tid] += t;
    __syncthreads();
  }
  if (i < n) data[i] = s[tid] - v;  // exclusive
  if (tid == 1023) bsum[blockIdx.x] = s[1023];
}

__global__ void __launch_bounds__(1024)
scan_add2(int* __restrict__ data, const int* __restrict__ bsum, int* __restrict__ cursor,
          int n, int ncur, int nb) {
  __shared__ int sb[128];
  int tid = threadIdx.x;
  if (tid < 128) sb[tid] = (tid < nb) ? bsum[tid] : 0;
  __syncthreads();
  for (int off = 1; off < 128; off <<= 1) {
    int t = (tid < 128 && tid >= off) ? sb[tid - off] : 0;
    __syncthreads();
    if (tid < 128) sb[tid] += t;   // inclusive
    __syncthreads();
  }
  int add = (blockIdx.x == 0) ? 0 : sb[blockIdx.x - 1];
  int i = blockIdx.x * 1024 + tid;
  if (i < n) {
    int v = data[i] + add;
    data[i] = v;
    if (i < ncur) cursor[i] = v;
  }
}

__global__ void fill_kernel(const int* __restrict__ src, const int* __restrict__ dst,
                            int* __restrict__ cursor, int* __restrict__ esrc, int E) {
  int i = blockIdx.x * blockDim.x + threadIdx.x;
  int stride = gridDim.x * blockDim.x;
  for (int e = i; e < E; e += stride) {
    int d = dst[e];
    int p = atomicAdd(&cursor[d], 1);
    esrc[p] = src[e];
  }
}

// blin passed as pointer + index (device memory cannot be read on host)
template <int K, bool AF32, bool FIRST>
__global__ void __launch_bounds__(256, 4)
gemm_kernel(const void* __restrict__ Ain, const unsigned short* __restrict__ Bpack,
            const float* __restrict__ bias, const float* __restrict__ bn,
            const float* __restrict__ wlin, const float* __restrict__ blin, int lidx,
            const int* __restrict__ batch, unsigned short* __restrict__ hout,
            float* __restrict__ node_pred, unsigned* __restrict__ wsi, int N) {
  __shared__ char s_a[16384];
  __shared__ float s_head[64][2];
  __shared__ unsigned s_wsi[NGRAPH];
  gemm_tile<K, AF32, FIRST>(blockIdx.x, Ain, Bpack, bias, bn, wlin, blin[lidx], batch,
                            hout, node_pred, wsi, N, s_a, s_head, s_wsi);
}

__global__ void __launch_bounds__(256)
agg_kernel(const unsigned short* __restrict__ h, const int* __restrict__ offsets,
           const int* __restrict__ esrc, unsigned short* __restrict__ tmp, int N) {
  agg_body(h, offsets, esrc, tmp, N);
}

__global__ void finalize_small(const unsigned* __restrict__ wsi, float* __restrict__ out) {
  int g = threadIdx.x;
  if (g < NGRAPH) out[g] = fdec(wsi[g]) + fdec(wsi[NGRAPH + g]) + fdec(wsi[2 * NGRAPH + g]);
}

// ---------------------------------------------------------------------------

extern "C" void kernel_launch(void* const* d_in, const int* in_sizes, int n_in,
                              void* d_out, int out_size, void* d_ws, size_t ws_size,
                              hipStream_t stream) {
  KArgs a;
  a.x        = (const float*)d_in[0];
  const int* ei = (const int*)d_in[1];
  a.batch    = (const int*)d_in[2];
  a.w_first  = (const float*)d_in[3];
  a.b_first  = (const float*)d_in[4];
  a.bn_first = (const float*)d_in[5];
  a.w_conv   = (const float*)d_in[6];
  a.b_conv   = (const float*)d_in[7];
  a.bn_conv  = (const float*)d_in[8];
  a.w_lin    = (const float*)d_in[9];
  a.b_lin    = (const float*)d_in[10];
  a.out = (float*)d_out;

  a.N = in_sizes[0] / D_IN;
  a.E = in_sizes[1] / 2;
  a.src = ei;
  a.dst = ei + a.E;
  a.ntiles = (a.N + 63) / 64;
  a.nchunks = (a.N + 1 + 255) / 256;   // 391 for N=100000 (must be <= 512)

  char* ws = (char*)d_ws;
  a.h   = (unsigned short*)ws;
  a.tmp = a.h + (size_t)a.N * H;
  a.wTf = a.tmp + (size_t)a.N * H;
  a.wTc = a.wTf + H * D_IN;
  a.offsets = (int*)(a.wTc + 2 * H * H);
  a.cursor  = a.offsets + (a.N + 1);
  a.esrc    = a.cursor + a.N;
  a.csum    = a.esrc + a.E;            // 512 ints (doubles as fallback scan bsum)
  a.wsi     = (unsigned*)(a.csum + 512);

  // ---- cooperative path: size the grid from the runtime's occupancy answer
  hipError_t lerr = hipErrorUnknown;
  int maxB = 0;
  if (hipOccupancyMaxActiveBlocksPerMultiprocessor(&maxB, mega_kernel, 256, 0) == hipSuccess &&
      maxB > 0) {
    int dev = 0, nCU = 0;
    hipGetDevice(&dev);
    if (hipDeviceGetAttribute(&nCU, hipDeviceAttributeMultiprocessorCount, dev) != hipSuccess ||
        nCU <= 0)
      nCU = 256;
    long long cap = (long long)maxB * nCU;
    int grid = (cap > 768) ? 768 : (int)cap;
    if (grid >= 64) {
      void* kp[] = {(void*)&a};
      lerr = hipLaunchCooperativeKernel(mega_kernel, dim3(grid), dim3(256), kp, 0, stream);
    }
  }

  if (lerr != hipSuccess) {
    // ---- fallback: proven multi-dispatch pipeline (identical arithmetic)
    const int N = a.N, E = a.E;
    const int gemm_grid = a.ntiles;
    const int nscan = N + 1;
    const int nb = (nscan + 1023) / 1024;
    float* node_pred = a.out + NGRAPH;

    init_prep_kernel<<<(N + 256) / 256, 256, 0, stream>>>(a.offsets, nscan, a.wsi,
                                                          a.w_first, a.w_conv, a.wTf, a.wTc);
    count_kernel<<<1024, 256, 0, stream>>>(a.dst, a.offsets, E);
    scan_local<<<nb, 1024, 0, stream>>>(a.offsets, a.csum, nscan);
    scan_add2<<<nb, 1024, 0, stream>>>(a.offsets, a.csum, a.cursor, nscan, N, nb);
    fill_kernel<<<1024, 256, 0, stream>>>(a.src, a.dst, a.cursor, a.esrc, E);

    gemm_kernel<D_IN, true, true><<<gemm_grid, 256, 0, stream>>>(
        a.x, a.wTf, a.b_first, a.bn_first, a.w_lin, a.b_lin, 0, a.batch, a.h,
        node_pred, a.wsi, N);
    agg_kernel<<<(N + 3) / 4, 256, 0, stream>>>(a.h, a.offsets, a.esrc, a.tmp, N);
    gemm_kernel<H, false, false><<<gemm_grid, 256, 0, stream>>>(
        a.tmp, a.wTc, a.b_conv, a.bn_conv, a.w_lin + H, a.b_lin, 1, a.batch, a.h,
        node_pred, a.wsi + NGRAPH, N);
    agg_kernel<<<(N + 3) / 4, 256, 0, stream>>>(a.h, a.offsets, a.esrc, a.tmp, N);
    gemm_kernel<H, false, false><<<gemm_grid, 256, 0, stream>>>(
        a.tmp, a.wTc + 16384, a.b_conv + H, a.bn_conv + 4 * H, a.w_lin + 2 * H, a.b_lin, 2,
        a.batch, a.h, node_pred, a.wsi + 2 * NGRAPH, N);
    finalize_small<<<1, 64, 0, stream>>>(a.wsi, a.out);
  }
}

// Round 22
// 250.514 us; speedup vs baseline: 3.3272x; 3.3272x over previous
//
#include <hip/hip_runtime.h>
#include <hip/hip_bf16.h>

#define H 128
#define D_IN 256
#define NGRAPH 8

typedef __attribute__((ext_vector_type(8))) short bf16x8;
typedef __attribute__((ext_vector_type(4))) float f32x4;
typedef __attribute__((ext_vector_type(4))) int i32x4;

// ---- order-preserving float<->unsigned encoding for max-reduction
__device__ __forceinline__ unsigned fenc(float f) {
  unsigned u = __float_as_uint(f);
  return (u & 0x80000000u) ? ~u : (u | 0x80000000u);
}
__device__ __forceinline__ float fdec(unsigned e) {
  unsigned v = (e & 0x80000000u) ? (e & 0x7FFFFFFFu) : ~e;
  return __uint_as_float(v);
}
__device__ __forceinline__ unsigned short f2bf(float f) {  // RNE f32->bf16
  unsigned u = __float_as_uint(f);
  unsigned r = u + 0x7FFFu + ((u >> 16) & 1u);
  return (unsigned short)(r >> 16);
}

// Fused: zero offsets[0..n1) + pack weights to bf16 fragment order
// Bpack[s][c][g][j] = w[s*32+g*8+j][c]
__global__ void init_prep_kernel(int* __restrict__ offsets, int n1,
                                 const float* __restrict__ wf, const float* __restrict__ wcv,
                                 unsigned short* __restrict__ Bf, unsigned short* __restrict__ Bc) {
  int i = blockIdx.x * 256 + threadIdx.x;
  if (i < n1) offsets[i] = 0;
  if (i < 32768) {                          // first layer: K=256, 8 k-steps
    int s = i >> 12, r = i & 4095;
    int c = r >> 5, r2 = r & 31;
    int g = r2 >> 3, j = r2 & 7;
    int k = s * 32 + g * 8 + j;
    Bf[i] = f2bf(wf[k * H + c]);
  } else if (i < 65536) {                   // conv layers: K=128, 4 k-steps each
    int i2 = i - 32768;
    int l = i2 >> 14, r = i2 & 16383;
    int s = r >> 12, rr = r & 4095;
    int c = rr >> 5, r2 = rr & 31;
    int g = r2 >> 3, j = r2 & 7;
    int k = s * 32 + g * 8 + j;
    Bc[i2] = f2bf(wcv[l * H * H + k * H + c]);
  }
}

__global__ void count_kernel(const int* __restrict__ dst, int* __restrict__ offsets, int E) {
  int i = blockIdx.x * blockDim.x + threadIdx.x;
  int stride = gridDim.x * blockDim.x;
  for (int e = i; e < E; e += stride) atomicAdd(&offsets[dst[e]], 1);
}

__global__ void __launch_bounds__(1024)
scan_local(int* __restrict__ data, int* __restrict__ bsum, int n) {
  __shared__ int s[1024];
  int tid = threadIdx.x;
  int i = blockIdx.x * 1024 + tid;
  int v = (i < n) ? data[i] : 0;
  s[tid] = v;
  __syncthreads();
  for (int off = 1; off < 1024; off <<= 1) {
    int t = (tid >= off) ? s[tid - off] : 0;
    __syncthreads();
    s[tid] += t;
    __syncthreads();
  }
  if (i < n) data[i] = s[tid] - v;  // exclusive
  if (tid == 1023) bsum[blockIdx.x] = s[1023];
}

// scan_add with INLINE bsum scan (each block redundantly scans <=128 partials)
__global__ void __launch_bounds__(1024)
scan_add2(int* __restrict__ data, const int* __restrict__ bsum, int* __restrict__ cursor,
          int n, int ncur, int nb) {
  __shared__ int sb[128];
  int tid = threadIdx.x;
  if (tid < 128) sb[tid] = (tid < nb) ? bsum[tid] : 0;
  __syncthreads();
  for (int off = 1; off < 128; off <<= 1) {
    int t = (tid < 128 && tid >= off) ? sb[tid - off] : 0;
    __syncthreads();
    if (tid < 128) sb[tid] += t;   // inclusive
    __syncthreads();
  }
  int add = (blockIdx.x == 0) ? 0 : sb[blockIdx.x - 1];
  int i = blockIdx.x * 1024 + tid;
  if (i < n) {
    int v = data[i] + add;
    data[i] = v;
    if (i < ncur) cursor[i] = v;
  }
}

__global__ void fill_kernel(const int* __restrict__ src, const int* __restrict__ dst,
                            int* __restrict__ cursor, int* __restrict__ esrc, int E) {
  int i = blockIdx.x * blockDim.x + threadIdx.x;
  int stride = gridDim.x * blockDim.x;
  for (int e = i; e < E; e += stride) {
    int d = dst[e];
    int p = atomicAdd(&cursor[d], 1);
    esrc[p] = src[e];
  }
}

// Fused GEMM [N x K] @ [K x 128] + bias + BN(eval) + ReLU -> h (bf16),
// plus linear head -> node_pred and per-graph segment-max partials -> slot.
// Round-15 proven config (session best, 252.4 us): BK=128 LDS chunks with
// coalesced register staging + XOR swizzle, packed-B fragment loads,
// BM=64, 4 waves 2x2, wave tile 32x64, launch_bounds(256,4).
template <int K, bool AF32, bool FIRST>
__global__ void __launch_bounds__(256, 4)
gemm_kernel(const void* __restrict__ Ain, const unsigned short* __restrict__ Bpack,
            const float* __restrict__ bias, const float* __restrict__ bn,
            const float* __restrict__ wlin, const float* __restrict__ blin, int lidx,
            const int* __restrict__ batch, unsigned short* __restrict__ hout,
            float* __restrict__ node_pred, unsigned* __restrict__ slot, int N) {
  constexpr int BK = 128;              // staged K-chunk (bf16 cols)
  constexpr int RB = BK * 2;           // 256 B per row in LDS
  constexpr int NCHUNK = K / BK;
  __shared__ char s_a[64 * RB];        // 16 KB A chunk, swizzled; reused as h-store tile
  __shared__ float s_head[64][2];      // per-row linear-head partials (wc halves)
  __shared__ unsigned s_wsi[NGRAPH];
  const int tid = threadIdx.x;
  const int wid = tid >> 6, lane = tid & 63;
  const int wr = wid >> 1, wc = wid & 1;
  const int g = lane >> 4, l15 = lane & 15;
  const int row0blk = blockIdx.x * 64;
  if (tid < NGRAPH) s_wsi[tid] = 0u;

  f32x4 acc[2][4] = {};
  const int lrow0 = wr * 32;

  for (int ch = 0; ch < NCHUNK; ++ch) {
    // ---- stage A chunk [64 rows][128 bf16 cols], coalesced, swizzled
    if (AF32) {
      const float* A = (const float*)Ain;
#pragma unroll
      for (int it = 0; it < 8; ++it) {
        int flat = (it * 256 + tid) * 4;      // f32 index in 64x128 chunk
        int lr = flat >> 7;
        int col = flat & 127;
        int grow = row0blk + lr;
        grow = (grow < N) ? grow : (N - 1);
        float4 u = *(const float4*)(A + (size_t)grow * K + ch * BK + col);
        union { unsigned short hh[4]; uint2 d; } pk;
        pk.hh[0] = f2bf(u.x); pk.hh[1] = f2bf(u.y);
        pk.hh[2] = f2bf(u.z); pk.hh[3] = f2bf(u.w);
        int addr = lr * RB + col * 2;
        *(uint2*)(s_a + (addr ^ ((lr & 7) << 4))) = pk.d;
      }
    } else {
      const char* A = (const char*)Ain;
#pragma unroll
      for (int it = 0; it < 4; ++it) {
        int unit = it * 256 + tid;            // 16-B unit in 64x256B chunk
        int lr = unit >> 4;
        int cb = (unit & 15) * 16;
        int grow = row0blk + lr;
        grow = (grow < N) ? grow : (N - 1);
        i32x4 q = *(const i32x4*)(A + (size_t)grow * (K * 2) + ch * RB + cb);
        int addr = lr * RB + cb;
        *(i32x4*)(s_a + (addr ^ ((lr & 7) << 4))) = q;
      }
    }
    __syncthreads();

    // ---- 4 k-steps on this chunk (LDS A + coalesced packed-B loads)
#pragma unroll
    for (int s = 0; s < 4; ++s) {
      int sg = ch * 4 + s;                    // global k-step for Bpack
      bf16x8 bfr[4];
#pragma unroll
      for (int n = 0; n < 4; ++n) {
        int c = wc * 64 + n * 16 + l15;
        bfr[n] = *(const bf16x8*)(Bpack + sg * 4096 + c * 32 + g * 8);
      }
      bf16x8 af[2];
#pragma unroll
      for (int m = 0; m < 2; ++m) {
        int lr = lrow0 + m * 16 + l15;
        int addr = lr * RB + s * 64 + g * 16;
        af[m] = *(const bf16x8*)(s_a + (addr ^ ((lr & 7) << 4)));
      }
#pragma unroll
      for (int m = 0; m < 2; ++m)
#pragma unroll
        for (int n = 0; n < 4; ++n)
          acc[m][n] = __builtin_amdgcn_mfma_f32_16x16x32_bf16(af[m], bfr[n], acc[m][n], 0, 0, 0);
    }
    __syncthreads();  // before restage / epilogue LDS reuse
  }

  // ---- epilogue: bias+BN+ReLU folded to hv = acc*sc + sh
  float sc[4], sh[4], wl[4];
#pragma unroll
  for (int n = 0; n < 4; ++n) {
    int c = wc * 64 + n * 16 + l15;
    float gam = bn[c], bet = bn[H + c], mu = bn[2 * H + c], va = bn[3 * H + c];
    float rs = rsqrtf(va + 1e-5f);
    sc[n] = gam * rs;
    sh[n] = (bias[c] - mu) * gam * rs + bet;
    wl[n] = wlin[c];
  }

  char* aw = s_a + wid * 2048;  // per-wave 16x64 bf16 tile region
#pragma unroll
  for (int m = 0; m < 2; ++m) {
    float pj[4] = {0.f, 0.f, 0.f, 0.f};
#pragma unroll
    for (int n = 0; n < 4; ++n)
#pragma unroll
      for (int j = 0; j < 4; ++j) {
        float hv = fmaxf(acc[m][n][j] * sc[n] + sh[n], 0.f);
        pj[j] += hv * wl[n];
        *(unsigned short*)(aw + (g * 4 + j) * 128 + (n * 16 + l15) * 2) = f2bf(hv);
      }
    // head partial: reduce across the 16 lanes (l15) of this g-group
#pragma unroll
    for (int j = 0; j < 4; ++j) {
      pj[j] += __shfl_xor(pj[j], 1);
      pj[j] += __shfl_xor(pj[j], 2);
      pj[j] += __shfl_xor(pj[j], 4);
      pj[j] += __shfl_xor(pj[j], 8);
    }
    if (l15 == 0) {
#pragma unroll
      for (int j = 0; j < 4; ++j)
        s_head[wr * 32 + m * 16 + g * 4 + j][wc] = pj[j];
    }
    // coalesced bf16 h store (wave-private LDS bounce; DS in-order, no barrier)
    int grb = row0blk + wr * 32 + m * 16;
#pragma unroll
    for (int it = 0; it < 2; ++it) {
      int bo = lane * 16 + it * 1024;
      int r16 = bo >> 7, inrow = bo & 127;
      if (grb + r16 < N)
        *(i32x4*)((char*)hout + (size_t)(grb + r16) * 256 + wc * 128 + inrow) =
            *(i32x4*)(aw + bo);
    }
  }
  __syncthreads();
  // finish head: one thread per block-row; per-graph max into LDS only
  if (tid < 64) {
    int grh = row0blk + tid;
    if (grh < N) {
      float np = s_head[tid][0] + s_head[tid][1] + blin[lidx];
      if (FIRST) node_pred[grh] = np; else node_pred[grh] += np;
      atomicMax(&s_wsi[batch[grh]], fenc(np));
    }
  }
  __syncthreads();
  // per-block slot store: PLAIN coalesced write, zero global contention
  if (tid < NGRAPH) slot[blockIdx.x * NGRAPH + tid] = s_wsi[tid];
}

// tmp[i] = h[i] + sum_{j in-edges} h[src_j]  (separate kernel: 100k waves TLP)
__global__ void __launch_bounds__(256)
agg_kernel(const unsigned short* __restrict__ h, const int* __restrict__ offsets,
           const int* __restrict__ esrc, unsigned short* __restrict__ tmp, int n) {
  int node = blockIdx.x * 4 + (threadIdx.x >> 6);
  if (node >= n) return;
  int lane = threadIdx.x & 63;  // 2 features per lane
  const unsigned* hw = (const unsigned*)h;
  size_t base = (size_t)node * (H / 2) + lane;
  unsigned u = hw[base];
  float a0 = __uint_as_float((u & 0xFFFFu) << 16);
  float a1 = __uint_as_float(u & 0xFFFF0000u);
  int s = offsets[node], e = offsets[node + 1];
  int j = s;
  for (; j + 4 <= e; j += 4) {
    int i0 = esrc[j], i1 = esrc[j + 1], i2 = esrc[j + 2], i3 = esrc[j + 3];
    unsigned v0 = hw[(size_t)i0 * (H / 2) + lane];
    unsigned v1 = hw[(size_t)i1 * (H / 2) + lane];
    unsigned v2 = hw[(size_t)i2 * (H / 2) + lane];
    unsigned v3 = hw[(size_t)i3 * (H / 2) + lane];
    a0 += __uint_as_float((v0 & 0xFFFFu) << 16) + __uint_as_float((v1 & 0xFFFFu) << 16) +
          __uint_as_float((v2 & 0xFFFFu) << 16) + __uint_as_float((v3 & 0xFFFFu) << 16);
    a1 += __uint_as_float(v0 & 0xFFFF0000u) + __uint_as_float(v1 & 0xFFFF0000u) +
          __uint_as_float(v2 & 0xFFFF0000u) + __uint_as_float(v3 & 0xFFFF0000u);
  }
  for (; j < e; ++j) {
    unsigned v2 = hw[(size_t)esrc[j] * (H / 2) + lane];
    a0 += __uint_as_float((v2 & 0xFFFFu) << 16);
    a1 += __uint_as_float(v2 & 0xFFFF0000u);
  }
  unsigned r = ((unsigned)f2bf(a1) << 16) | (unsigned)f2bf(a0);
  ((unsigned*)tmp)[base] = r;
}

// out[g] = sum_l max_b slots[l][b][g]; 192 threads = 24 (l,g) pairs x 8 lanes
__global__ void __launch_bounds__(256)
finalize_kernel(const unsigned* __restrict__ slots, float* __restrict__ out, int nb) {
  __shared__ float red[3][NGRAPH];
  int tid = threadIdx.x;
  if (tid < 192) {
    int pair = tid >> 3, w = tid & 7;
    int l = pair >> 3, g = pair & 7;
    unsigned m = 0u;
    const unsigned* base = slots + (size_t)l * nb * NGRAPH + g;
    for (int b = w; b < nb; b += 8) m = max(m, base[b * NGRAPH]);
    m = max(m, (unsigned)__shfl_xor((int)m, 1));
    m = max(m, (unsigned)__shfl_xor((int)m, 2));
    m = max(m, (unsigned)__shfl_xor((int)m, 4));
    if (w == 0) red[l][g] = fdec(m);
  }
  __syncthreads();
  if (tid < NGRAPH) out[tid] = red[0][tid] + red[1][tid] + red[2][tid];
}

extern "C" void kernel_launch(void* const* d_in, const int* in_sizes, int n_in,
                              void* d_out, int out_size, void* d_ws, size_t ws_size,
                              hipStream_t stream) {
  const float* x        = (const float*)d_in[0];
  const int*   ei       = (const int*)d_in[1];
  const int*   batch    = (const int*)d_in[2];
  const float* w_first  = (const float*)d_in[3];
  const float* b_first  = (const float*)d_in[4];
  const float* bn_first = (const float*)d_in[5];
  const float* w_conv   = (const float*)d_in[6];
  const float* b_conv   = (const float*)d_in[7];
  const float* bn_conv  = (const float*)d_in[8];
  const float* w_lin    = (const float*)d_in[9];
  const float* b_lin    = (const float*)d_in[10];
  float* out = (float*)d_out;

  const int N = in_sizes[0] / D_IN;
  const int E = in_sizes[1] / 2;
  const int* src = ei;
  const int* dst = ei + E;

  const int gemm_grid = (N + 63) / 64;

  char* ws = (char*)d_ws;
  unsigned short* h   = (unsigned short*)ws;            // N*H bf16
  unsigned short* tmp = h + (size_t)N * H;              // N*H bf16
  unsigned short* wTf = tmp + (size_t)N * H;            // 32768 bf16 (packed w_first)
  unsigned short* wTc = wTf + H * D_IN;                 // 32768 bf16 (packed w_conv x2)
  int* offsets = (int*)(wTc + 2 * H * H);
  int* cursor  = offsets + (N + 1);
  int* esrc    = cursor + N;
  int* bsum    = esrc + E;                              // scan block sums (<=128)
  unsigned* slots = (unsigned*)(bsum + 128);            // [3][gemm_grid][8]
  float* node_pred = out + NGRAPH;

  const int nscan = N + 1;
  const int nb = (nscan + 1023) / 1024;                 // 98 for N=100000 (<=128)

  init_prep_kernel<<<(N + 256) / 256, 256, 0, stream>>>(offsets, nscan, w_first, w_conv,
                                                        wTf, wTc);
  count_kernel<<<1024, 256, 0, stream>>>(dst, offsets, E);
  scan_local<<<nb, 1024, 0, stream>>>(offsets, bsum, nscan);
  scan_add2<<<nb, 1024, 0, stream>>>(offsets, bsum, cursor, nscan, N, nb);
  fill_kernel<<<1024, 256, 0, stream>>>(src, dst, cursor, esrc, E);

  gemm_kernel<D_IN, true, true><<<gemm_grid, 256, 0, stream>>>(
      x, wTf, b_first, bn_first, w_lin, b_lin, 0, batch, h, node_pred, slots, N);
  for (int l = 0; l < 2; ++l) {
    agg_kernel<<<(N + 3) / 4, 256, 0, stream>>>(h, offsets, esrc, tmp, N);
    gemm_kernel<H, false, false><<<gemm_grid, 256, 0, stream>>>(
        tmp, wTc + (size_t)l * 16384, b_conv + (size_t)l * H, bn_conv + (size_t)l * 4 * H,
        w_lin + (size_t)(l + 1) * H, b_lin, l + 1, batch, h, node_pred,
        slots + (size_t)(l + 1) * gemm_grid * NGRAPH, N);
  }
  finalize_kernel<<<1, 256, 0, stream>>>(slots, out, gemm_grid);
}